// Round 1
// baseline (962.248 us; speedup 1.0000x reference)
//
#include <hip/hip_runtime.h>

#define B_DIM 2048
#define S_IN  4096
#define S_OUT 4096
#define KBINS 8
#define HID   1024
#define NPASS (B_DIM * S_IN)   // 8388608

typedef __attribute__((ext_vector_type(8))) short short8;
typedef __attribute__((ext_vector_type(4))) float f32x4;

__device__ inline void gld16(const void* g, void* l) {
    __builtin_amdgcn_global_load_lds((const __attribute__((address_space(1))) void*)g,
                                     (__attribute__((address_space(3))) void*)l, 16, 0, 0);
}

__device__ inline unsigned short f2bf(float f) {
    union { float f; unsigned u; } v; v.f = f;
    unsigned r = v.u + 0x7fffu + ((v.u >> 16) & 1u);   // round-to-nearest-even
    return (unsigned short)(r >> 16);
}

__device__ inline float tanh_fast(float x) {
    // tanh(x) = 1 - 2/(exp(2x)+1); stable for large |x| (exp->0 or inf)
    float e = __expf(2.0f * x);
    return 1.0f - 2.0f / (e + 1.0f);
}

// ---------------------------------------------------------------- init
__global__ void init_k(const float* __restrict__ logd, float* __restrict__ ld,
                       float* __restrict__ red) {
    int i = blockIdx.x * blockDim.x + threadIdx.x;
    if (i < B_DIM) ld[i] = logd[i];
    if (i < 2) red[i] = 0.0f;
}

// ---------------------------------------------------------------- mean/std reduction
__global__ __launch_bounds__(256) void reduce_k(const float* __restrict__ xp,
                                                float* __restrict__ red) {
    float s = 0.0f, s2 = 0.0f;
    int stride = gridDim.x * blockDim.x;
    for (int i = blockIdx.x * blockDim.x + threadIdx.x; i < NPASS / 4; i += stride) {
        float4 v = ((const float4*)xp)[i];
        s  += v.x + v.y + v.z + v.w;
        s2 += v.x * v.x + v.y * v.y + v.z * v.z + v.w * v.w;
    }
#pragma unroll
    for (int o = 32; o > 0; o >>= 1) { s += __shfl_down(s, o); s2 += __shfl_down(s2, o); }
    __shared__ float bs[4], bs2[4];
    int lane = threadIdx.x & 63, w = threadIdx.x >> 6;
    if (lane == 0) { bs[w] = s; bs2[w] = s2; }
    __syncthreads();
    if (threadIdx.x == 0) {
        atomicAdd(&red[0], bs[0] + bs[1] + bs[2] + bs[3]);
        atomicAdd(&red[1], bs2[0] + bs2[1] + bs2[2] + bs2[3]);
    }
}

// ---------------------------------------------------------------- standardize -> bf16
__global__ __launch_bounds__(256) void convxn_k(const float* __restrict__ xp,
                                                const float* __restrict__ red,
                                                unsigned short* __restrict__ xn) {
    float s0 = red[0], s1 = red[1];
    float mean = s0 * (1.0f / (float)NPASS);
    float var  = (s1 - s0 * mean) * (1.0f / (float)(NPASS - 1));
    float rstd = 1.0f / sqrtf(var);
    int stride = gridDim.x * blockDim.x;
    for (int i = blockIdx.x * blockDim.x + threadIdx.x; i < NPASS / 4; i += stride) {
        float4 v = ((const float4*)xp)[i];
        union { unsigned short u[4]; uint2 v2; } o;
        o.u[0] = f2bf((v.x - mean) * rstd);
        o.u[1] = f2bf((v.y - mean) * rstd);
        o.u[2] = f2bf((v.z - mean) * rstd);
        o.u[3] = f2bf((v.w - mean) * rstd);
        ((uint2*)xn)[i] = o.v2;
    }
}

// ---------------------------------------------------------------- transpose + convert f32[R][C] -> bf16[C][R]
__global__ __launch_bounds__(256) void convT_k(const float* __restrict__ in,
                                               unsigned short* __restrict__ out,
                                               int R, int C) {
    __shared__ float t[64][65];
    int c0 = blockIdx.x * 64, r0 = blockIdx.y * 64;
    int tx = threadIdx.x & 15, ty = threadIdx.x >> 4;
#pragma unroll
    for (int rr = 0; rr < 4; ++rr) {
        float4 v = *(const float4*)&in[(size_t)(r0 + ty + rr * 16) * C + c0 + tx * 4];
        t[ty + rr * 16][tx * 4 + 0] = v.x;
        t[ty + rr * 16][tx * 4 + 1] = v.y;
        t[ty + rr * 16][tx * 4 + 2] = v.z;
        t[ty + rr * 16][tx * 4 + 3] = v.w;
    }
    __syncthreads();
#pragma unroll
    for (int rr = 0; rr < 4; ++rr) {
        int c = ty + rr * 16;
        union { unsigned short u[4]; uint2 v2; } o;
#pragma unroll
        for (int k2 = 0; k2 < 4; ++k2) o.u[k2] = f2bf(t[tx * 4 + k2][c]);
        *(uint2*)&out[(size_t)(c0 + c) * R + r0 + tx * 4] = o.v2;
    }
}

// ---------------------------------------------------------------- GEMM1: h = tanh(xn @ W1 + b1), bf16 out
// A [2048][4096] bf16, Bt [1024][4096] bf16, H [2048][1024] bf16
__global__ __launch_bounds__(256) void gemm1_k(const unsigned short* __restrict__ A,
                                               const unsigned short* __restrict__ Bt,
                                               const float* __restrict__ bias,
                                               unsigned short* __restrict__ H) {
    constexpr int K = S_IN, N = HID;
    __shared__ unsigned short As[128 * 32], Bs[128 * 32];
    const int tid = threadIdx.x;
    const int m0 = blockIdx.y * 128, n0 = blockIdx.x * 128;
    const int lane = tid & 63, w = tid >> 6, wm = w >> 1, wn = w & 1;
    const int ra = lane & 15, qa = lane >> 4;
    const unsigned short* gA = A + (size_t)(m0 + (tid >> 2)) * K + (tid & 3) * 8;
    const unsigned short* gB = Bt + (size_t)(n0 + (tid >> 2)) * K + (tid & 3) * 8;
    unsigned short* lA = As + tid * 8;
    unsigned short* lB = Bs + tid * 8;
    f32x4 acc[4][4] = {};
    for (int kt = 0; kt < K; kt += 32) {
        gld16(gA + kt, lA);
        gld16(gA + kt + (size_t)64 * K, lA + 256 * 8);
        gld16(gB + kt, lB);
        gld16(gB + kt + (size_t)64 * K, lB + 256 * 8);
        __syncthreads();
        short8 af[4], bg[4];
#pragma unroll
        for (int i = 0; i < 4; ++i)
            af[i] = *(const short8*)&As[(wm * 64 + i * 16 + ra) * 32 + qa * 8];
#pragma unroll
        for (int j = 0; j < 4; ++j)
            bg[j] = *(const short8*)&Bs[(wn * 64 + j * 16 + ra) * 32 + qa * 8];
#pragma unroll
        for (int i = 0; i < 4; ++i)
#pragma unroll
            for (int j = 0; j < 4; ++j)
                acc[i][j] = __builtin_amdgcn_mfma_f32_16x16x32_bf16(af[i], bg[j], acc[i][j], 0, 0, 0);
        __syncthreads();
    }
#pragma unroll
    for (int i = 0; i < 4; ++i) {
        int row = m0 + wm * 64 + i * 16 + qa * 4;
#pragma unroll
        for (int j = 0; j < 4; ++j) {
            int col = n0 + wn * 64 + j * 16 + ra;
            float bv = bias[col];
#pragma unroll
            for (int r = 0; r < 4; ++r)
                H[(size_t)(row + r) * N + col] = f2bf(tanh_fast(acc[i][j][r] + bv));
        }
    }
}

// ---------------------------------------------------------------- GEMM2 + fused spline epilogue
// A = h [2048][1024] bf16, Bt = W2t [32768][1024] bf16
__global__ __launch_bounds__(256) void gemm2_k(const unsigned short* __restrict__ A,
                                               const unsigned short* __restrict__ Bt,
                                               const float* __restrict__ bias,
                                               const float* __restrict__ x_in,
                                               float* __restrict__ phi,
                                               float* __restrict__ ld) {
    constexpr int K = HID;
    __shared__ union {
        struct { unsigned short A[4096]; unsigned short B[4096]; } st;
        float ct[64 * 132];
    } sm;
    const int tid = threadIdx.x;
    const int m0 = blockIdx.y * 128, n0 = blockIdx.x * 128;
    const int lane = tid & 63, w = tid >> 6, wm = w >> 1, wn = w & 1;
    const int ra = lane & 15, qa = lane >> 4;
    const unsigned short* gA = A + (size_t)(m0 + (tid >> 2)) * K + (tid & 3) * 8;
    const unsigned short* gB = Bt + (size_t)(n0 + (tid >> 2)) * K + (tid & 3) * 8;
    unsigned short* lA = sm.st.A + tid * 8;
    unsigned short* lB = sm.st.B + tid * 8;
    f32x4 acc[4][4] = {};
    for (int kt = 0; kt < K; kt += 32) {
        gld16(gA + kt, lA);
        gld16(gA + kt + (size_t)64 * K, lA + 256 * 8);
        gld16(gB + kt, lB);
        gld16(gB + kt + (size_t)64 * K, lB + 256 * 8);
        __syncthreads();
        short8 af[4], bg[4];
#pragma unroll
        for (int i = 0; i < 4; ++i)
            af[i] = *(const short8*)&sm.st.A[(wm * 64 + i * 16 + ra) * 32 + qa * 8];
#pragma unroll
        for (int j = 0; j < 4; ++j)
            bg[j] = *(const short8*)&sm.st.B[(wn * 64 + j * 16 + ra) * 32 + qa * 8];
#pragma unroll
        for (int i = 0; i < 4; ++i)
#pragma unroll
            for (int j = 0; j < 4; ++j)
                acc[i][j] = __builtin_amdgcn_mfma_f32_16x16x32_bf16(af[i], bg[j], acc[i][j], 0, 0, 0);
        __syncthreads();
    }
    const int sb = n0 >> 3;  // first spline index of this tile (16 per tile)
    for (int hh = 0; hh < 2; ++hh) {
        __syncthreads();
        if (wm == hh) {
#pragma unroll
            for (int i = 0; i < 4; ++i) {
                int lr = i * 16 + qa * 4;
#pragma unroll
                for (int j = 0; j < 4; ++j) {
                    int c = wn * 64 + j * 16 + ra;
                    float bv = bias[n0 + c];
#pragma unroll
                    for (int r = 0; r < 4; ++r)
                        sm.ct[(lr + r) * 132 + c] = tanh_fast(acc[i][j][r] + bv);
                }
            }
        }
        __syncthreads();
        int row = tid >> 2, q4 = tid & 3;
        int grow = m0 + hh * 64 + row;
        float4 xv4 = *(const float4*)&x_in[(size_t)grow * S_OUT + sb + q4 * 4];
        float xa[4] = {xv4.x, xv4.y, xv4.z, xv4.w};
        float neglog = 0.0f;
#pragma unroll
        for (int gi = 0; gi < 4; ++gi) {
            int g = q4 * 4 + gi;
            const float* cp = &sm.ct[row * 132 + g * 8];
            float tt[8], ee[8], es = 0.0f;
#pragma unroll
            for (int k2 = 0; k2 < 8; ++k2) {
                tt[k2] = cp[k2];
                ee[k2] = __expf(tt[k2]);
                es += ee[k2];
            }
            float x = xa[gi] / 3.14159274101257324f;           // x_in / pi (f32)
            float fk = (x + 1e-6f) * (8.0f / (1.0f + 2e-6f));  // searchsorted equivalent
            int kb = (int)fk;
            kb = kb > 7 ? 7 : kb;
            float cum = 0.0f, ek = ee[0], tk = tt[0];
#pragma unroll
            for (int k2 = 1; k2 < 8; ++k2) {
                cum += (k2 <= kb) ? ee[k2 - 1] : 0.0f;
                ek = (k2 == kb) ? ee[k2] : ek;
                tk = (k2 == kb) ? tt[k2] : tk;
            }
            float invS = 1.0f / es;
            float alpha = x * 8.0f - (float)kb;
            phi[(size_t)grow * S_OUT + sb + g] = (cum + alpha * ek) * invS;
            neglog += __logf(es) - tk;  // -log p_k
        }
        neglog += __shfl_xor(neglog, 1);
        neglog += __shfl_xor(neglog, 2);
        if (q4 == 0) atomicAdd(&ld[grow], neglog);
    }
}

// ---------------------------------------------------------------- launch
extern "C" void kernel_launch(void* const* d_in, const int* in_sizes, int n_in,
                              void* d_out, int out_size, void* d_ws, size_t ws_size,
                              hipStream_t stream) {
    const float* x_in      = (const float*)d_in[0];
    const float* x_passive = (const float*)d_in[1];
    const float* logd      = (const float*)d_in[2];
    const float* W1        = (const float*)d_in[3];
    const float* b1        = (const float*)d_in[4];
    const float* W2        = (const float*)d_in[5];
    const float* b2        = (const float*)d_in[6];
    float* phi = (float*)d_out;
    float* ld  = phi + (size_t)B_DIM * S_OUT;

    char* ws = (char*)d_ws;
    float* red           = (float*)ws;
    unsigned short* xn   = (unsigned short*)(ws + 256);
    unsigned short* W1t  = (unsigned short*)(ws + 256 + 16777216);               // 8.4M xn bf16
    unsigned short* W2t  = (unsigned short*)(ws + 256 + 16777216 + 8388608);     // + W1t
    unsigned short* h    = (unsigned short*)(ws + 256 + 16777216 + 8388608 + 67108864); // + W2t

    hipLaunchKernelGGL(init_k, dim3(8), dim3(256), 0, stream, logd, ld, red);
    hipLaunchKernelGGL(reduce_k, dim3(1024), dim3(256), 0, stream, x_passive, red);
    hipLaunchKernelGGL(convxn_k, dim3(2048), dim3(256), 0, stream, x_passive, red, xn);
    hipLaunchKernelGGL(convT_k, dim3(HID / 64, S_IN / 64), dim3(256), 0, stream, W1, W1t, S_IN, HID);
    hipLaunchKernelGGL(convT_k, dim3(S_OUT * KBINS / 64, HID / 64), dim3(256), 0, stream, W2, W2t, HID, S_OUT * KBINS);
    hipLaunchKernelGGL(gemm1_k, dim3(HID / 128, B_DIM / 128), dim3(256), 0, stream, xn, W1t, b1, h);
    hipLaunchKernelGGL(gemm2_k, dim3(S_OUT * KBINS / 128, B_DIM / 128), dim3(256), 0, stream, h, W2t, b2, x_in, phi, ld);
}

// Round 2
// 719.824 us; speedup vs baseline: 1.3368x; 1.3368x over previous
//
#include <hip/hip_runtime.h>

#define B_DIM 2048
#define S_IN  4096
#define S_OUT 4096
#define KBINS 8
#define HID   1024
#define NPASS (B_DIM * S_IN)   // 8388608

typedef __attribute__((ext_vector_type(8))) short short8;
typedef __attribute__((ext_vector_type(4))) float f32x4;

__device__ inline void gld16(const void* g, void* l) {
    __builtin_amdgcn_global_load_lds((const __attribute__((address_space(1))) void*)g,
                                     (__attribute__((address_space(3))) void*)l, 16, 0, 0);
}

__device__ inline unsigned short f2bf(float f) {
    union { float f; unsigned u; } v; v.f = f;
    unsigned r = v.u + 0x7fffu + ((v.u >> 16) & 1u);   // round-to-nearest-even
    return (unsigned short)(r >> 16);
}

__device__ inline float tanh_fast(float x) {
    float e = __expf(2.0f * x);
    return 1.0f - 2.0f / (e + 1.0f);
}

// ---------------------------------------------------------------- init
__global__ void init_k(const float* __restrict__ logd, float* __restrict__ ld,
                       float* __restrict__ red) {
    int i = blockIdx.x * blockDim.x + threadIdx.x;
    if (i < B_DIM) ld[i] = logd[i];
    if (i < 2) red[i] = 0.0f;
}

// ---------------------------------------------------------------- mean/std reduction
__global__ __launch_bounds__(256) void reduce_k(const float* __restrict__ xp,
                                                float* __restrict__ red) {
    float s = 0.0f, s2 = 0.0f;
    int stride = gridDim.x * blockDim.x;
    for (int i = blockIdx.x * blockDim.x + threadIdx.x; i < NPASS / 4; i += stride) {
        float4 v = ((const float4*)xp)[i];
        s  += v.x + v.y + v.z + v.w;
        s2 += v.x * v.x + v.y * v.y + v.z * v.z + v.w * v.w;
    }
#pragma unroll
    for (int o = 32; o > 0; o >>= 1) { s += __shfl_down(s, o); s2 += __shfl_down(s2, o); }
    __shared__ float bs[4], bs2[4];
    int lane = threadIdx.x & 63, w = threadIdx.x >> 6;
    if (lane == 0) { bs[w] = s; bs2[w] = s2; }
    __syncthreads();
    if (threadIdx.x == 0) {
        atomicAdd(&red[0], bs[0] + bs[1] + bs[2] + bs[3]);
        atomicAdd(&red[1], bs2[0] + bs2[1] + bs2[2] + bs2[3]);
    }
}

// ---------------------------------------------------------------- standardize -> bf16
__global__ __launch_bounds__(256) void convxn_k(const float* __restrict__ xp,
                                                const float* __restrict__ red,
                                                unsigned short* __restrict__ xn) {
    float s0 = red[0], s1 = red[1];
    float mean = s0 * (1.0f / (float)NPASS);
    float var  = (s1 - s0 * mean) * (1.0f / (float)(NPASS - 1));
    float rstd = 1.0f / sqrtf(var);
    int stride = gridDim.x * blockDim.x;
    for (int i = blockIdx.x * blockDim.x + threadIdx.x; i < NPASS / 4; i += stride) {
        float4 v = ((const float4*)xp)[i];
        union { unsigned short u[4]; uint2 v2; } o;
        o.u[0] = f2bf((v.x - mean) * rstd);
        o.u[1] = f2bf((v.y - mean) * rstd);
        o.u[2] = f2bf((v.z - mean) * rstd);
        o.u[3] = f2bf((v.w - mean) * rstd);
        ((uint2*)xn)[i] = o.v2;
    }
}

// ---------------------------------------------------------------- transpose + convert f32[R][C] -> bf16[C][R]
__global__ __launch_bounds__(256) void convT_k(const float* __restrict__ in,
                                               unsigned short* __restrict__ out,
                                               int R, int C) {
    __shared__ float t[64][65];
    int c0 = blockIdx.x * 64, r0 = blockIdx.y * 64;
    int tx = threadIdx.x & 15, ty = threadIdx.x >> 4;
#pragma unroll
    for (int rr = 0; rr < 4; ++rr) {
        float4 v = *(const float4*)&in[(size_t)(r0 + ty + rr * 16) * C + c0 + tx * 4];
        t[ty + rr * 16][tx * 4 + 0] = v.x;
        t[ty + rr * 16][tx * 4 + 1] = v.y;
        t[ty + rr * 16][tx * 4 + 2] = v.z;
        t[ty + rr * 16][tx * 4 + 3] = v.w;
    }
    __syncthreads();
#pragma unroll
    for (int rr = 0; rr < 4; ++rr) {
        int c = ty + rr * 16;
        union { unsigned short u[4]; uint2 v2; } o;
#pragma unroll
        for (int k2 = 0; k2 < 4; ++k2) o.u[k2] = f2bf(t[tx * 4 + k2][c]);
        *(uint2*)&out[(size_t)(c0 + c) * R + r0 + tx * 4] = o.v2;
    }
}

// ---------------------------------------------------------------- GEMM1: h = tanh(xn @ W1 + b1)
// BM=64, BN=128, BK=32, double-buffered, swizzled. A [2048][4096], Bt [1024][4096], H [2048][1024] bf16
__global__ __launch_bounds__(256) void gemm1_k(const unsigned short* __restrict__ A,
                                               const unsigned short* __restrict__ Bt,
                                               const float* __restrict__ bias,
                                               unsigned short* __restrict__ H) {
    constexpr int K = S_IN, N = HID;
    __shared__ unsigned short As[2][2048], Bs[2][4096];   // 8 + 16 = 24 KB
    const int tid = threadIdx.x;
    const int m0 = blockIdx.y * 64, n0 = blockIdx.x * 128;
    const int lane = tid & 63, w = tid >> 6, wm = w >> 1, wn = w & 1;
    const int ra = lane & 15, qa = lane >> 4;
    const int qs = qa ^ (ra & 3);                         // swizzled k-slot for fragment reads
    const int rowL = tid >> 2, slotL = (tid & 3) ^ (rowL & 3);
    const unsigned short* gA = A + (size_t)(m0 + rowL) * K + slotL * 8;
    const unsigned short* gB = Bt + (size_t)(n0 + rowL) * K + slotL * 8;

    f32x4 acc[2][4] = {};
    auto stage = [&](int buf, int kt) {
        gld16(gA + kt, &As[buf][tid * 8]);
        gld16(gB + kt, &Bs[buf][tid * 8]);
        gld16(gB + kt + (size_t)64 * K, &Bs[buf][tid * 8 + 2048]);
    };
    stage(0, 0);
    __syncthreads();
    int cur = 0;
    for (int kt = 0; kt < K; kt += 32, cur ^= 1) {
        if (kt + 32 < K) stage(cur ^ 1, kt + 32);
        short8 af[2], bg[4];
#pragma unroll
        for (int i = 0; i < 2; ++i) {
            int r = wm * 32 + i * 16 + ra;
            af[i] = *(const short8*)&As[cur][r * 32 + qs * 8];
        }
#pragma unroll
        for (int j = 0; j < 4; ++j) {
            int c = wn * 64 + j * 16 + ra;
            bg[j] = *(const short8*)&Bs[cur][c * 32 + qs * 8];
        }
#pragma unroll
        for (int i = 0; i < 2; ++i)
#pragma unroll
            for (int j = 0; j < 4; ++j)
                acc[i][j] = __builtin_amdgcn_mfma_f32_16x16x32_bf16(af[i], bg[j], acc[i][j], 0, 0, 0);
        __syncthreads();
    }
#pragma unroll
    for (int i = 0; i < 2; ++i) {
        int row = m0 + wm * 32 + i * 16 + qa * 4;
#pragma unroll
        for (int j = 0; j < 4; ++j) {
            int col = n0 + wn * 64 + j * 16 + ra;
            float bv = bias[col];
#pragma unroll
            for (int r = 0; r < 4; ++r)
                H[(size_t)(row + r) * N + col] = f2bf(tanh_fast(acc[i][j][r] + bv));
        }
    }
}

// ---------------------------------------------------------------- GEMM2 + fused spline epilogue
// BM=128, BN=128, BK=32, dbuf, swizzled. A = h [2048][1024], Bt = W2t [32768][1024]
__global__ __launch_bounds__(256) void gemm2_k(const unsigned short* __restrict__ A,
                                               const unsigned short* __restrict__ Bt,
                                               const float* __restrict__ bias,
                                               const float* __restrict__ x_in,
                                               float* __restrict__ phi,
                                               float* __restrict__ ld) {
    constexpr int K = HID;
    __shared__ union {
        unsigned short st[2][2][4096];   // [buf][A=0/B=1][128 rows * 32 cols]  = 32 KB
        float ct[32 * 140];              // epilogue tanh staging, stride 140   = 17.9 KB
    } sm;
    const int tid = threadIdx.x;
    // XCD-bijective swizzle: consecutive blocks within an XCD share a W2t panel
    int eff = (blockIdx.x & 7) * 512 + (blockIdx.x >> 3);
    const int m0 = (eff & 15) * 128, n0 = (eff >> 4) * 128;
    const int lane = tid & 63, w = tid >> 6, wm = w >> 1, wn = w & 1;
    const int ra = lane & 15, qa = lane >> 4;
    const int qs = qa ^ (ra & 3);
    const int rowL = tid >> 2, slotL = (tid & 3) ^ (rowL & 3);
    const unsigned short* gA = A + (size_t)(m0 + rowL) * K + slotL * 8;
    const unsigned short* gB = Bt + (size_t)(n0 + rowL) * K + slotL * 8;

    f32x4 acc[4][4] = {};
    auto stage = [&](int buf, int kt) {
        gld16(gA + kt, &sm.st[buf][0][tid * 8]);
        gld16(gA + kt + (size_t)64 * K, &sm.st[buf][0][tid * 8 + 2048]);
        gld16(gB + kt, &sm.st[buf][1][tid * 8]);
        gld16(gB + kt + (size_t)64 * K, &sm.st[buf][1][tid * 8 + 2048]);
    };
    stage(0, 0);
    __syncthreads();
    int cur = 0;
    for (int kt = 0; kt < K; kt += 32, cur ^= 1) {
        if (kt + 32 < K) stage(cur ^ 1, kt + 32);
        short8 af[4], bg[4];
#pragma unroll
        for (int i = 0; i < 4; ++i) {
            int r = wm * 64 + i * 16 + ra;
            af[i] = *(const short8*)&sm.st[cur][0][r * 32 + qs * 8];
        }
#pragma unroll
        for (int j = 0; j < 4; ++j) {
            int c = wn * 64 + j * 16 + ra;
            bg[j] = *(const short8*)&sm.st[cur][1][c * 32 + qs * 8];
        }
#pragma unroll
        for (int i = 0; i < 4; ++i)
#pragma unroll
            for (int j = 0; j < 4; ++j)
                acc[i][j] = __builtin_amdgcn_mfma_f32_16x16x32_bf16(af[i], bg[j], acc[i][j], 0, 0, 0);
        __syncthreads();
    }

    // ---- fused epilogue: tanh -> softmax(K=8) -> spline, 4 phases of 32 rows
    const int sb = n0 >> 3;               // first spline group of this tile (16 per tile)
    float bv[4];
#pragma unroll
    for (int j = 0; j < 4; ++j) bv[j] = bias[n0 + wn * 64 + j * 16 + ra];
    const int erow = tid >> 3;            // 0..31
    const int gp = tid & 7;               // 0..7 (2 spline groups each)
#pragma unroll
    for (int p = 0; p < 4; ++p) {
        if (wm == (p >> 1)) {
#pragma unroll
            for (int ii = 0; ii < 2; ++ii) {
                int i = (p & 1) * 2 + ii;
#pragma unroll
                for (int j = 0; j < 4; ++j) {
                    int c = wn * 64 + j * 16 + ra;
#pragma unroll
                    for (int r = 0; r < 4; ++r)
                        sm.ct[(ii * 16 + qa * 4 + r) * 140 + c] = tanh_fast(acc[i][j][r] + bv[j]);
                }
            }
        }
        __syncthreads();
        int grow = m0 + p * 32 + erow;
        float2 xv = *(const float2*)&x_in[(size_t)grow * S_OUT + sb + gp * 2];
        float xs[2] = {xv.x, xv.y};
        float res[2];
        float neglog = 0.0f;
#pragma unroll
        for (int gi = 0; gi < 2; ++gi) {
            const float* cp = &sm.ct[erow * 140 + (gp * 2 + gi) * 8];
            float4 c0 = *(const float4*)cp;
            float4 c1 = *(const float4*)(cp + 4);
            float tt[8] = {c0.x, c0.y, c0.z, c0.w, c1.x, c1.y, c1.z, c1.w};
            float ee[8], es = 0.0f;
#pragma unroll
            for (int k2 = 0; k2 < 8; ++k2) { ee[k2] = __expf(tt[k2]); es += ee[k2]; }
            float x = xs[gi] / 3.14159274101257324f;           // x_in / pi
            float fk = (x + 1e-6f) * (8.0f / (1.0f + 2e-6f));  // searchsorted equivalent
            int kb = (int)fk;
            kb = kb > 7 ? 7 : kb;
            float cum = 0.0f, ek = ee[0], tk = tt[0];
#pragma unroll
            for (int k2 = 1; k2 < 8; ++k2) {
                cum += (k2 <= kb) ? ee[k2 - 1] : 0.0f;
                ek = (k2 == kb) ? ee[k2] : ek;
                tk = (k2 == kb) ? tt[k2] : tk;
            }
            float alpha = x * 8.0f - (float)kb;
            res[gi] = (cum + alpha * ek) / es;
            neglog += __logf(es) - tk;                         // -log p_k
        }
        *(float2*)&phi[(size_t)grow * S_OUT + sb + gp * 2] = make_float2(res[0], res[1]);
        neglog += __shfl_xor(neglog, 1);
        neglog += __shfl_xor(neglog, 2);
        neglog += __shfl_xor(neglog, 4);
        if (gp == 0) atomicAdd(&ld[grow], neglog);
        __syncthreads();
    }
}

// ---------------------------------------------------------------- launch
extern "C" void kernel_launch(void* const* d_in, const int* in_sizes, int n_in,
                              void* d_out, int out_size, void* d_ws, size_t ws_size,
                              hipStream_t stream) {
    const float* x_in      = (const float*)d_in[0];
    const float* x_passive = (const float*)d_in[1];
    const float* logd      = (const float*)d_in[2];
    const float* W1        = (const float*)d_in[3];
    const float* b1        = (const float*)d_in[4];
    const float* W2        = (const float*)d_in[5];
    const float* b2        = (const float*)d_in[6];
    float* phi = (float*)d_out;
    float* ld  = phi + (size_t)B_DIM * S_OUT;

    char* ws = (char*)d_ws;
    float* red           = (float*)ws;
    unsigned short* xn   = (unsigned short*)(ws + 256);
    unsigned short* W1t  = (unsigned short*)(ws + 256 + 16777216);
    unsigned short* W2t  = (unsigned short*)(ws + 256 + 16777216 + 8388608);
    unsigned short* h    = (unsigned short*)(ws + 256 + 16777216 + 8388608 + 67108864);

    hipLaunchKernelGGL(init_k, dim3(8), dim3(256), 0, stream, logd, ld, red);
    hipLaunchKernelGGL(reduce_k, dim3(1024), dim3(256), 0, stream, x_passive, red);
    hipLaunchKernelGGL(convxn_k, dim3(2048), dim3(256), 0, stream, x_passive, red, xn);
    hipLaunchKernelGGL(convT_k, dim3(HID / 64, S_IN / 64), dim3(256), 0, stream, W1, W1t, S_IN, HID);
    hipLaunchKernelGGL(convT_k, dim3(S_OUT * KBINS / 64, HID / 64), dim3(256), 0, stream, W2, W2t, HID, S_OUT * KBINS);
    hipLaunchKernelGGL(gemm1_k, dim3(HID / 128, B_DIM / 64), dim3(256), 0, stream, xn, W1t, b1, h);
    hipLaunchKernelGGL(gemm2_k, dim3(4096), dim3(256), 0, stream, h, W2t, b2, x_in, phi, ld);
}